// Round 1
// baseline (281.535 us; speedup 1.0000x reference)
//
#include <hip/hip_runtime.h>

// Problem constants: B=32768, K=64, D=64, GAIN=1.0
#define LOG_2PI 1.8378770664093453f

typedef __attribute__((ext_vector_type(8))) short  short8;   // 8 x bf16 (4 VGPRs)
typedef __attribute__((ext_vector_type(4))) float  float4_;  // 4 x f32

__device__ __forceinline__ short f2bf(float f) {
  unsigned u = __builtin_bit_cast(unsigned, f);
  u += 0x7fffu + ((u >> 16) & 1u);   // round-to-nearest-even
  return (short)(u >> 16);
}

template <int CTRL>
__device__ __forceinline__ float dpp_add(float v) {
  int t = __builtin_amdgcn_mov_dpp(__builtin_bit_cast(int, v), CTRL, 0xf, 0xf, true);
  return v + __builtin_bit_cast(float, t);
}

// ---------------------------------------------------------------------------
// Setup: per component k compute Linv (forward substitution), M = Linv^T Linv,
// W = bf16(-0.5*M) row-major, c = M*mu (fp32), beta (fp32).
// ---------------------------------------------------------------------------
__global__ __launch_bounds__(64) void gmm_setup(
    const float* __restrict__ means_raw, const float* __restrict__ scale_raw,
    const float* __restrict__ weights_raw,
    unsigned short* __restrict__ W, float* __restrict__ cvec,
    float* __restrict__ beta)
{
  const int k = blockIdx.x;
  const int tid = threadIdx.x;  // 64 threads
  __shared__ float P[64][65];   // pre (lower) with exponentiated diagonal
  __shared__ float V[64][65];   // Linv (lower)
  __shared__ float mu[64];
  __shared__ float red[64];
  __shared__ float hld_s;

  const float sp = 1.0f / 512.0f;   // GAIN/sqrt(K*D*D)
  for (int i = 0; i < 64; ++i)
    P[i][tid] = scale_raw[(size_t)k * 4096 + i * 64 + tid] * sp;
  mu[tid] = means_raw[k * 64 + tid] * (1.0f / 64.0f);  // GAIN/sqrt(K*D)
  __syncthreads();

  if (tid == 0) {                 // half_log_det = sum(diag(pre))
    float h = 0.f;
    for (int i = 0; i < 64; ++i) h += P[i][i];
    hld_s = h;
  }
  __syncthreads();
  P[tid][tid] = expf(P[tid][tid]);  // L diagonal = exp(diag(pre))
  __syncthreads();

  // Forward substitution, column j per thread: L*V = I (columns independent).
  {
    const int j = tid;
    float vprev = 1.0f / P[j][j];
    V[j][j] = vprev;
    for (int i = j + 1; i < 64; ++i) {
      float s = P[i][i - 1] * vprev;            // freshest term kept in reg
      for (int m = j; m < i - 1; ++m) s += P[i][m] * V[m][j];
      vprev = -s / P[i][i];
      V[i][j] = vprev;
    }
  }
  __syncthreads();

  // M row i per thread: M[i][j] = sum_{m>=max(i,j)} V[m][i]*V[m][j]
  {
    const int i = tid;
    float ci = 0.f;
    for (int j = 0; j < 64; ++j) {
      const int lo = i > j ? i : j;
      float m = 0.f;
      for (int mm = lo; mm < 64; ++mm) m += V[mm][i] * V[mm][j];
      ci += m * mu[j];
      W[(size_t)k * 4096 + i * 64 + j] = (unsigned short)f2bf(-0.5f * m);
    }
    cvec[k * 64 + i] = ci;
    red[i] = ci * mu[i];
  }
  __syncthreads();

  if (tid == 0) {
    float q = 0.f;
    for (int i = 0; i < 64; ++i) q += red[i];
    // log_softmax over weights_raw/8 (redundant per block; trivial)
    float wk = weights_raw[k] * 0.125f;
    float mx = -3.0e38f;
    for (int t = 0; t < 64; ++t) mx = fmaxf(mx, weights_raw[t] * 0.125f);
    float se = 0.f;
    for (int t = 0; t < 64; ++t) se += expf(weights_raw[t] * 0.125f - mx);
    float logw = wk - mx - logf(se);
    beta[k] = -0.5f * q - 32.0f * LOG_2PI - hld_s + logw;
  }
}

// ---------------------------------------------------------------------------
// Main: 256 blocks x 256 threads; block owns 128 rows, wave owns 32 (2 m-tiles).
// val[b,k] = x^T(-0.5 M_k)x + c_k.x + beta_k via mfma_f32_16x16x32_bf16 with
// C-operand initialized to c_k; epilogue = C-layout dot with xc + DPP reduce +
// shifted-exp accumulation; logsumexp shift fixed at +90.
// ---------------------------------------------------------------------------
__global__ __launch_bounds__(256) void gmm_main(
    const float* __restrict__ x, const unsigned short* __restrict__ W,
    const float* __restrict__ cvec, const float* __restrict__ beta,
    float* __restrict__ partials)
{
  // 144 B padded row stride: conflict-free for stage writes and B-frag reads
  __shared__ __align__(16) unsigned short Wlds[2][64][72];
  __shared__ float wsum[4];

  const int tid = threadIdx.x;
  const int lane = tid & 63;
  const int wv = tid >> 6;
  const int q = lane >> 4;     // quad
  const int lr = lane & 15;
  const int rowBase = blockIdx.x * 128 + wv * 32;

  // A fragments (A[m=lane&15][k=quad*8+j]), built once from x
  short8 a[2][2];
#pragma unroll
  for (int mt = 0; mt < 2; ++mt)
#pragma unroll
    for (int ks = 0; ks < 2; ++ks) {
      const float* xp = x + (size_t)(rowBase + mt * 16 + lr) * 64 + ks * 32 + q * 8;
      const float4_* xv = (const float4_*)xp;
      float4_ lo = xv[0], hi = xv[1];
      short8 v;
      v[0] = f2bf(lo[0]); v[1] = f2bf(lo[1]); v[2] = f2bf(lo[2]); v[3] = f2bf(lo[3]);
      v[4] = f2bf(hi[0]); v[5] = f2bf(hi[1]); v[6] = f2bf(hi[2]); v[7] = f2bf(hi[3]);
      a[mt][ks] = v;
    }

  // fp32 copy of x in C layout: xc[mt][t][r] = x[rowBase+mt*16+4q+r][lr+16t]
  float xc[2][4][4];
#pragma unroll
  for (int mt = 0; mt < 2; ++mt)
#pragma unroll
    for (int r = 0; r < 4; ++r) {
      const float* xp = x + (size_t)(rowBase + mt * 16 + q * 4 + r) * 64 + lr;
#pragma unroll
      for (int t = 0; t < 4; ++t) xc[mt][t][r] = xp[16 * t];
    }

  // W staging: thread covers 32 B of the 8 KB W_k tile
  const int srow = tid >> 2;       // 0..63
  const int squarter = tid & 3;    // 0..3
  const unsigned short* wg = W + (size_t)srow * 64 + squarter * 16;
  {
    const float4_* g = (const float4_*)wg;
    float4_ s0 = g[0], s1 = g[1];
    float4_* l = (float4_*)(&Wlds[0][srow][squarter * 16]);
    l[0] = s0; l[1] = s1;
  }

  float ccreg[2][4];
  float betreg[2];
  const float* cl = cvec + lr;
#pragma unroll
  for (int t = 0; t < 4; ++t) ccreg[0][t] = cl[16 * t];
  betreg[0] = beta[0];

  float sacc[2][4] = {{0.f, 0.f, 0.f, 0.f}, {0.f, 0.f, 0.f, 0.f}};

  __syncthreads();

  for (int k = 0; k < 64; ++k) {
    const int cur = k & 1;

    // B fragments for k from LDS (lane: col n=lr+16t, kdim slice q*8+32ks)
    short8 b[2][4];
#pragma unroll
    for (int t = 0; t < 4; ++t)
#pragma unroll
      for (int ks = 0; ks < 2; ++ks)
        b[ks][t] = *(const short8*)(&Wlds[cur][lr + 16 * t][8 * q + 32 * ks]);

    // prefetch k+1 (global -> regs; landed into LDS after the MFMAs)
    float4_ s0, s1;
    if (k < 63) {
      const float4_* g = (const float4_*)(wg + (size_t)(k + 1) * 4096);
      s0 = g[0]; s1 = g[1];
#pragma unroll
      for (int t = 0; t < 4; ++t) ccreg[cur ^ 1][t] = cl[(k + 1) * 64 + 16 * t];
      betreg[cur ^ 1] = beta[k + 1];
    }

    // MFMAs: 16 per wave per k, C initialized with c_k (column-broadcast)
    float4_ f[2][4];
#pragma unroll
    for (int mt = 0; mt < 2; ++mt)
#pragma unroll
      for (int t = 0; t < 4; ++t) {
        const float cv = ccreg[cur][t];
        float4_ acc = {cv, cv, cv, cv};
        acc = __builtin_amdgcn_mfma_f32_16x16x32_bf16(a[mt][0], b[0][t], acc, 0, 0, 0);
        acc = __builtin_amdgcn_mfma_f32_16x16x32_bf16(a[mt][1], b[1][t], acc, 0, 0, 0);
        f[mt][t] = acc;
      }

    // stage k+1 into the other LDS buffer
    if (k < 63) {
      float4_* l = (float4_*)(&Wlds[cur ^ 1][srow][squarter * 16]);
      l[0] = s0; l[1] = s1;
    }

    // epilogue: row-dot with x, DPP rotate-reduce over the 16-lane col group,
    // shifted exp accumulate
    const float bet = betreg[cur] + 90.0f;
#pragma unroll
    for (int mt = 0; mt < 2; ++mt) {
#pragma unroll
      for (int r = 0; r < 4; ++r) {
        float sdot = xc[mt][0][r] * f[mt][0][r];
        sdot += xc[mt][1][r] * f[mt][1][r];
        sdot += xc[mt][2][r] * f[mt][2][r];
        sdot += xc[mt][3][r] * f[mt][3][r];
        sdot = dpp_add<0x121>(sdot);  // row_ror:1
        sdot = dpp_add<0x122>(sdot);  // row_ror:2
        sdot = dpp_add<0x124>(sdot);  // row_ror:4
        sdot = dpp_add<0x128>(sdot);  // row_ror:8
        sacc[mt][r] += __expf(sdot + bet);
      }
    }
    __syncthreads();
  }

  // lp[b] = log(sacc) - 90; rows are replicated across the 16-lane group
  float p = 0.f;
  if (lr == 0) {
#pragma unroll
    for (int mt = 0; mt < 2; ++mt)
#pragma unroll
      for (int r = 0; r < 4; ++r)
        p += logf(sacc[mt][r]) - 90.0f;
  }
  p += __shfl_xor(p, 16, 64);
  p += __shfl_xor(p, 32, 64);
  if (lane == 0) wsum[wv] = p;
  __syncthreads();
  if (tid == 0) partials[blockIdx.x] = wsum[0] + wsum[1] + wsum[2] + wsum[3];
}

// ---------------------------------------------------------------------------
__global__ __launch_bounds__(256) void gmm_final(const float* __restrict__ partials,
                                                 float* __restrict__ out)
{
  const int tid = threadIdx.x;
  float v = partials[tid];
#pragma unroll
  for (int d = 1; d < 64; d <<= 1) v += __shfl_xor(v, d, 64);
  __shared__ float s[4];
  if ((tid & 63) == 0) s[tid >> 6] = v;
  __syncthreads();
  if (tid == 0) out[0] = -(s[0] + s[1] + s[2] + s[3]) * (1.0f / 32768.0f);
}

extern "C" void kernel_launch(void* const* d_in, const int* in_sizes, int n_in,
                              void* d_out, int out_size, void* d_ws, size_t ws_size,
                              hipStream_t stream)
{
  const float* x           = (const float*)d_in[0];  // [32768,64]
  const float* means_raw   = (const float*)d_in[1];  // [64,64]
  const float* scale_raw   = (const float*)d_in[2];  // [64,64,64]
  const float* weights_raw = (const float*)d_in[3];  // [64]
  float* out = (float*)d_out;

  // workspace layout (542 KB total)
  char* ws = (char*)d_ws;
  unsigned short* W = (unsigned short*)ws;                       // 524288 B
  float* cvec       = (float*)(ws + 524288);                     //  16384 B
  float* beta       = (float*)(ws + 524288 + 16384);             //    256 B
  float* partials   = (float*)(ws + 524288 + 16384 + 256);       //   1024 B

  gmm_setup<<<64, 64, 0, stream>>>(means_raw, scale_raw, weights_raw, W, cvec, beta);
  gmm_main<<<256, 256, 0, stream>>>(x, W, cvec, beta, partials);
  gmm_final<<<1, 256, 0, stream>>>(partials, out);
}

// Round 2
// 130.527 us; speedup vs baseline: 2.1569x; 2.1569x over previous
//
#include <hip/hip_runtime.h>

// B=32768, K=64, D=64, GAIN=1.0
#define LOG_2PI 1.8378770664093453f

typedef __attribute__((ext_vector_type(8))) short  short8;   // 8 x bf16
typedef __attribute__((ext_vector_type(4))) float  float4_;
typedef __attribute__((ext_vector_type(4))) unsigned int uint4_;

__device__ __forceinline__ unsigned short f2bf(float f) {
  unsigned u = __builtin_bit_cast(unsigned, f);
  u += 0x7fffu + ((u >> 16) & 1u);   // RNE
  return (unsigned short)(u >> 16);
}

template <int CTRL>
__device__ __forceinline__ float dpp_add(float v) {
  int t = __builtin_amdgcn_mov_dpp(__builtin_bit_cast(int, v), CTRL, 0xf, 0xf, true);
  return v + __builtin_bit_cast(float, t);
}

__device__ __forceinline__ void async16(const void* g, void* l) {
  __builtin_amdgcn_global_load_lds((const __attribute__((address_space(1))) unsigned int*)g,
                                   (__attribute__((address_space(3))) unsigned int*)l, 16, 0, 0);
}

// ---------------------------------------------------------------------------
// Setup: one block per component k (256 threads).
//  Phase 1: load pre = scale_raw/512 as transposed strict-lower Plt[m][i]
//           (zeros elsewhere), diag dg, rdg = 1/exp(diag).
//  Phase 2: wave0: forward substitution, column j per lane, s[64] in regs,
//           broadcast b128 Plt reads.  wave1: log_softmax of weights.
//  Phase 3: M[i][j] = sum_m Vt[i][m]*Vt[j][m]; emit W pre-swizzled as the
//           main kernel's padded LDS image (row stride 72 shorts), c, beta.
// ---------------------------------------------------------------------------
__global__ __launch_bounds__(256) void gmm_setup(
    const float* __restrict__ means_raw, const float* __restrict__ scale_raw,
    const float* __restrict__ weights_raw,
    unsigned short* __restrict__ Wf, float* __restrict__ cvec,
    float* __restrict__ beta)
{
  const int k = blockIdx.x;
  const int t = threadIdx.x;
  const int lane = t & 63;
  const int wv = t >> 6;

  __shared__ float Plt[64][68];   // Plt[m][i] = L[i][m] for i>m, else 0
  __shared__ float Vt[64][68];    // Vt[c][m]  = Linv[m][c]
  __shared__ float dg[64], rdg[64], mu_s[64], red[64];
  __shared__ float cpart[4][64];
  __shared__ float lw_s;

  {  // phase 1: thread t loads 16 contiguous floats of row i
    const int i = t >> 2;
    const int c0 = (t & 3) * 16;
    float4_ v4[4];
    const float4_* src = (const float4_*)(scale_raw + (size_t)k * 4096 + i * 64 + c0);
    v4[0] = src[0]; v4[1] = src[1]; v4[2] = src[2]; v4[3] = src[3];
#pragma unroll
    for (int e = 0; e < 16; ++e) {
      const int c = c0 + e;
      const float val = ((const float*)v4)[e] * (1.0f / 512.0f);
      Plt[c][i] = (c < i) ? val : 0.0f;
      if (c == i) { dg[i] = val; rdg[i] = __expf(-val); }
    }
  }
  if (t < 64) mu_s[t] = means_raw[k * 64 + t] * (1.0f / 64.0f);
  __syncthreads();

  if (wv == 0) {
    // forward substitution: lane = column j of Linv
    const int j = lane;
    float s[64];
#pragma unroll
    for (int i = 0; i < 64; ++i) s[i] = 0.0f;
#pragma unroll
    for (int m = 0; m < 64; ++m) {
      const float r = rdg[m];              // LDS broadcast
      float v = -s[m] * r;                 // s[m]==0 for m<j -> v=0 there
      if (m == j) v = r;
      Vt[j][m] = v;
      const int i0 = (m + 1) & ~3;
#pragma unroll
      for (int i = i0; i < 64; i += 4) {   // Plt zero for i<=m: safe
        const float4_ p4 = *(const float4_*)&Plt[m][i];
        s[i + 0] += p4[0] * v;
        s[i + 1] += p4[1] * v;
        s[i + 2] += p4[2] * v;
        s[i + 3] += p4[3] * v;
      }
    }
  } else if (wv == 1) {
    // log_softmax of weights_raw/8 by wave butterfly
    float wr = weights_raw[lane] * 0.125f;
    float mx = wr;
#pragma unroll
    for (int d = 1; d < 64; d <<= 1) mx = fmaxf(mx, __shfl_xor(mx, d, 64));
    float se = __expf(wr - mx);
#pragma unroll
    for (int d = 1; d < 64; d <<= 1) se += __shfl_xor(se, d, 64);
    if (lane == k) lw_s = wr - mx - __logf(se);
  }
  __syncthreads();

  // phase 3: thread (i = lane, jgrp = wave) computes M[i][j], 16 j's
  {
    const int i = lane;
    const int jgrp = wv;
    float ci = 0.0f;
    unsigned wp[8];
#pragma unroll
    for (int jj = 0; jj < 16; ++jj) {
      const int j = jgrp * 16 + jj;
      const int m0 = j & ~3;               // Vt zero below max(i,j): safe
      float acc = 0.0f;
      for (int m = m0; m < 64; m += 4) {
        const float4_ va = *(const float4_*)&Vt[i][m];   // lane-strided, pad 68: conflict-free
        const float4_ vb = *(const float4_*)&Vt[j][m];   // broadcast
        acc += va[0] * vb[0] + va[1] * vb[1] + va[2] * vb[2] + va[3] * vb[3];
      }
      ci += acc * mu_s[j];
      const unsigned short h = f2bf(-0.5f * acc);
      if (jj & 1) wp[jj >> 1] |= ((unsigned)h << 16);
      else        wp[jj >> 1] = (unsigned)h;
    }
    // W image: per-k 64 rows x 72 shorts (pad junk), row i, cols jgrp*16..+15
    uint4_* dst = (uint4_*)(Wf + (size_t)k * 4608 + i * 72 + jgrp * 16);
    uint4_ d0 = {wp[0], wp[1], wp[2], wp[3]};
    uint4_ d1 = {wp[4], wp[5], wp[6], wp[7]};
    dst[0] = d0; dst[1] = d1;
    cpart[jgrp][i] = ci;
  }
  __syncthreads();
  if (t < 64) {
    const float cv = cpart[0][t] + cpart[1][t] + cpart[2][t] + cpart[3][t];
    cvec[k * 64 + t] = cv;
    red[t] = cv * mu_s[t];
  }
  __syncthreads();
  if (t == 0) {
    float hld = 0.0f, qq = 0.0f;
    for (int e = 0; e < 64; ++e) { hld += dg[e]; qq += red[e]; }
    beta[k] = -0.5f * qq - 32.0f * LOG_2PI - hld + lw_s;
  }
}

// ---------------------------------------------------------------------------
// Main: 512 blocks x 256 threads, 2 blocks/CU (2 waves/SIMD).
// blockIdx: rt = >>1 (128 rows), kh = &1 (32 components).
// Wave owns 32 rows (mt=2).  W staged via global_load_lds (16B), KG=2
// double-buffered (36.9 KB LDS).  Emits per-row partial exp-sums (shift +90).
// ---------------------------------------------------------------------------
__global__ __launch_bounds__(256, 2) void gmm_main(
    const float* __restrict__ x, const unsigned short* __restrict__ Wf,
    const float* __restrict__ cvec, const float* __restrict__ beta,
    float* __restrict__ ph)
{
  __shared__ __align__(16) unsigned short Wlds[2][2][4608];

  const int t = threadIdx.x;
  const int lane = t & 63;
  const int wv = t >> 6;
  const int q = lane >> 4;
  const int lr = lane & 15;
  const int kh = blockIdx.x & 1;
  const int rt = blockIdx.x >> 1;
  const int rowBase = rt * 128 + wv * 32;
  const int kbase = kh * 32;

  // A fragments: A[m=lr][kdim=8q+32ks+j]
  short8 a[2][2];
#pragma unroll
  for (int mt = 0; mt < 2; ++mt)
#pragma unroll
    for (int ks = 0; ks < 2; ++ks) {
      const float4_* xv = (const float4_*)(x + (size_t)(rowBase + mt * 16 + lr) * 64 + ks * 32 + q * 8);
      const float4_ lo = xv[0], hi = xv[1];
      short8 v;
      v[0] = f2bf(lo[0]); v[1] = f2bf(lo[1]); v[2] = f2bf(lo[2]); v[3] = f2bf(lo[3]);
      v[4] = f2bf(hi[0]); v[5] = f2bf(hi[1]); v[6] = f2bf(hi[2]); v[7] = f2bf(hi[3]);
      a[mt][ks] = v;
    }

  // fp32 x in C layout: xc[mt][t4][r] = x[rowBase+mt*16+4q+r][lr+16*t4]
  float xc[2][4][4];
#pragma unroll
  for (int mt = 0; mt < 2; ++mt)
#pragma unroll
    for (int r = 0; r < 4; ++r) {
      const float* xp = x + (size_t)(rowBase + mt * 16 + q * 4 + r) * 64 + lr;
#pragma unroll
      for (int t4 = 0; t4 < 4; ++t4) xc[mt][t4][r] = xp[16 * t4];
    }

  float cc[2][2][4];
  float bet[2][2];
  float sacc[2][4] = {{0, 0, 0, 0}, {0, 0, 0, 0}};

  // group g covers components kbase+2g, kbase+2g+1 (9216 shorts = 18432 B)
#define STAGE(g, slot)                                                          \
  {                                                                             \
    const unsigned short* src = Wf + (size_t)(kbase + 2 * (g)) * 4608 + t * 8;  \
    unsigned short* dst = &Wlds[slot][0][0] + t * 8;                            \
    async16(src,         dst);                                                  \
    async16(src + 2048,  dst + 2048);                                           \
    async16(src + 4096,  dst + 4096);                                           \
    async16(src + 6144,  dst + 6144);                                           \
    if (t < 128) async16(src + 8192, dst + 8192);                               \
  }
#define LOADCC(g, slot)                                                         \
  {                                                                             \
    const int k0 = kbase + 2 * (g);                                             \
    _Pragma("unroll") for (int kk = 0; kk < 2; ++kk) {                          \
      const float* cp = cvec + (k0 + kk) * 64 + lr;                             \
      _Pragma("unroll") for (int t4 = 0; t4 < 4; ++t4)                          \
        cc[slot][kk][t4] = cp[16 * t4];                                         \
      bet[slot][kk] = beta[k0 + kk] + 90.0f;                                    \
    }                                                                           \
  }

  STAGE(0, 0)
  LOADCC(0, 0)
  __syncthreads();

  for (int g = 0; g < 16; ++g) {
    const int cur = g & 1;
    if (g < 15) { STAGE(g + 1, cur ^ 1) LOADCC(g + 1, cur ^ 1) }
#pragma unroll
    for (int kk = 0; kk < 2; ++kk) {
      const unsigned short* wb = &Wlds[cur][kk][0];
      short8 b[2][4];
#pragma unroll
      for (int t4 = 0; t4 < 4; ++t4)
#pragma unroll
        for (int ks = 0; ks < 2; ++ks)
          b[ks][t4] = *(const short8*)(wb + (lr + 16 * t4) * 72 + 8 * q + 32 * ks);

      float4_ f[2][4];
#pragma unroll
      for (int mt = 0; mt < 2; ++mt)
#pragma unroll
        for (int t4 = 0; t4 < 4; ++t4) {
          const float cv = cc[cur][kk][t4];
          float4_ acc = {cv, cv, cv, cv};
          acc = __builtin_amdgcn_mfma_f32_16x16x32_bf16(a[mt][0], b[0][t4], acc, 0, 0, 0);
          acc = __builtin_amdgcn_mfma_f32_16x16x32_bf16(a[mt][1], b[1][t4], acc, 0, 0, 0);
          f[mt][t4] = acc;
        }

      const float bk = bet[cur][kk];
#pragma unroll
      for (int mt = 0; mt < 2; ++mt)
#pragma unroll
        for (int r = 0; r < 4; ++r) {
          float sdot = xc[mt][0][r] * f[mt][0][r] + xc[mt][1][r] * f[mt][1][r]
                     + xc[mt][2][r] * f[mt][2][r] + xc[mt][3][r] * f[mt][3][r];
          sdot = dpp_add<0x121>(sdot);  // row_ror:1
          sdot = dpp_add<0x122>(sdot);  // row_ror:2
          sdot = dpp_add<0x124>(sdot);  // row_ror:4
          sdot = dpp_add<0x128>(sdot);  // row_ror:8
          sacc[mt][r] += __expf(sdot + bk);
        }
    }
    __syncthreads();
  }

  // per-row partial sums (replicated across the 16-lane group; lr==0 stores)
  if (lr == 0) {
#pragma unroll
    for (int mt = 0; mt < 2; ++mt)
#pragma unroll
      for (int r = 0; r < 4; ++r)
        ph[(size_t)kh * 32768 + rowBase + mt * 16 + q * 4 + r] = sacc[mt][r];
  }
#undef STAGE
#undef LOADCC
}

// ---------------------------------------------------------------------------
__global__ __launch_bounds__(256) void gmm_final1(const float* __restrict__ ph,
                                                  float* __restrict__ p1)
{
  const int t = threadIdx.x;
  const int row = blockIdx.x * 512 + t;
  float v = __logf(ph[row] + ph[32768 + row])
          + __logf(ph[row + 256] + ph[32768 + row + 256]) - 180.0f;
#pragma unroll
  for (int d = 1; d < 64; d <<= 1) v += __shfl_xor(v, d, 64);
  __shared__ float s[4];
  if ((t & 63) == 0) s[t >> 6] = v;
  __syncthreads();
  if (t == 0) p1[blockIdx.x] = s[0] + s[1] + s[2] + s[3];
}

__global__ __launch_bounds__(64) void gmm_final2(const float* __restrict__ p1,
                                                 float* __restrict__ out)
{
  float v = p1[threadIdx.x];
#pragma unroll
  for (int d = 1; d < 64; d <<= 1) v += __shfl_xor(v, d, 64);
  if (threadIdx.x == 0) out[0] = -v * (1.0f / 32768.0f);
}

extern "C" void kernel_launch(void* const* d_in, const int* in_sizes, int n_in,
                              void* d_out, int out_size, void* d_ws, size_t ws_size,
                              hipStream_t stream)
{
  const float* x           = (const float*)d_in[0];  // [32768,64]
  const float* means_raw   = (const float*)d_in[1];  // [64,64]
  const float* scale_raw   = (const float*)d_in[2];  // [64,64,64]
  const float* weights_raw = (const float*)d_in[3];  // [64]
  float* out = (float*)d_out;

  // workspace layout (~849 KB)
  char* ws = (char*)d_ws;
  unsigned short* Wf = (unsigned short*)ws;                  // 64*4608*2 = 589824 B
  float* cvec = (float*)(ws + 589824);                       // 16384 B
  float* beta = (float*)(ws + 606208);                       // 256 B
  float* ph   = (float*)(ws + 606464);                       // 2*32768*4 = 262144 B
  float* p1   = (float*)(ws + 868608);                       // 256 B

  gmm_setup<<<64, 256, 0, stream>>>(means_raw, scale_raw, weights_raw, Wf, cvec, beta);
  gmm_main<<<512, 256, 0, stream>>>(x, Wf, cvec, beta, ph);
  gmm_final1<<<64, 256, 0, stream>>>(ph, p1);
  gmm_final2<<<1, 64, 0, stream>>>(p1, out);
}

// Round 3
// 109.368 us; speedup vs baseline: 2.5742x; 1.1935x over previous
//
#include <hip/hip_runtime.h>

// B=32768, K=64, D=64, GAIN=1.0
#define LOG_2PI 1.8378770664093453f

typedef __attribute__((ext_vector_type(8))) short  short8;   // 8 x bf16
typedef __attribute__((ext_vector_type(4))) float  float4_;

__device__ __forceinline__ unsigned short f2bf(float f) {
  unsigned u = __builtin_bit_cast(unsigned, f);
  u += 0x7fffu + ((u >> 16) & 1u);   // RNE
  return (unsigned short)(u >> 16);
}
__device__ __forceinline__ float bf2f(unsigned short h) {
  unsigned u = ((unsigned)h) << 16;
  return __builtin_bit_cast(float, u);
}
template <int CTRL>
__device__ __forceinline__ float dpp_add(float v) {
  int t = __builtin_amdgcn_mov_dpp(__builtin_bit_cast(int, v), CTRL, 0xf, 0xf, true);
  return v + __builtin_bit_cast(float, t);
}
__device__ __forceinline__ void async16(const void* g, void* l) {
  __builtin_amdgcn_global_load_lds((const __attribute__((address_space(1))) unsigned int*)g,
                                   (__attribute__((address_space(3))) unsigned int*)l, 16, 0, 0);
}

// ---------------------------------------------------------------------------
// Setup: one block per component k.
//  W image per comp (4608 shorts = 9216 B): row n in [0,64): shorts [0,64) =
//  bf16 W[n][:] = -0.5*M[n][:]; row n bytes [128,132) = fp32 c_n; row 0 bytes
//  [132,136) = fp32 beta. Pad rest junk (staged, never read).
//  Phase 2: 4 waves x (16 cols x 4 row-quarters) forward substitution,
//  s[16]/lane, pivot broadcast via shfl. Phase 3: M = V^T V via bf16 MFMA.
// ---------------------------------------------------------------------------
__global__ __launch_bounds__(256) void gmm_setup(
    const float* __restrict__ means_raw, const float* __restrict__ scale_raw,
    const float* __restrict__ weights_raw, unsigned short* __restrict__ Wf)
{
  const int k = blockIdx.x;
  const int t = threadIdx.x;
  const int lane = t & 63;
  const int wv = t >> 6;
  const int q = lane >> 4;
  const int jj = lane & 15;

  __shared__ float Plt[64][68];   // Plt[m][i] = L[i][m] for i>m, else 0
  __shared__ float Vt[64][68];    // Vt[c][m]  = Linv[m][c] (full 64x64)
  __shared__ __align__(16) unsigned short Vb[64][72];  // bf16 Vt image
  __shared__ float dg[64], rdg[64], mu_s[64], y_s[64];

  {  // phase 1: thread t loads 16 contiguous floats of row i
    const int i = t >> 2;
    const int c0 = (t & 3) * 16;
    float4_ v4[4];
    const float4_* src = (const float4_*)(scale_raw + (size_t)k * 4096 + i * 64 + c0);
    v4[0] = src[0]; v4[1] = src[1]; v4[2] = src[2]; v4[3] = src[3];
#pragma unroll
    for (int e = 0; e < 16; ++e) {
      const int c = c0 + e;
      const float val = ((const float*)v4)[e] * (1.0f / 512.0f);
      Plt[c][i] = (c < i) ? val : 0.0f;
      if (c == i) { dg[i] = val; rdg[i] = __expf(-val); }
    }
  }
  if (t < 64) mu_s[t] = means_raw[k * 64 + t] * (1.0f / 64.0f);
  __syncthreads();

  // phase 2: forward substitution. lane (q,jj) serves column j = wv*16+jj,
  // owns rows [16q,16q+16). Pivot v_m broadcast from owner quarter via shfl.
  {
    const int j = wv * 16 + jj;
    float s[16];
#pragma unroll
    for (int i = 0; i < 16; ++i) s[i] = 0.0f;
#pragma unroll
    for (int m = 0; m < 64; ++m) {
      const float rm = rdg[m];
      float vcand = (m == j) ? rm : -s[m & 15] * rm;   // valid on owner lane
      const float v = __shfl(vcand, (m >> 4) * 16 + jj, 64);
      if (q == (m >> 4)) {
        Vt[j][m] = v;
        Vb[j][m] = f2bf(v);
      }
      const float4_* prow = (const float4_*)&Plt[m][16 * q];
      const float4_ p0 = prow[0], p1 = prow[1], p2 = prow[2], p3 = prow[3];
      s[0]  += p0[0] * v; s[1]  += p0[1] * v; s[2]  += p0[2] * v; s[3]  += p0[3] * v;
      s[4]  += p1[0] * v; s[5]  += p1[1] * v; s[6]  += p1[2] * v; s[7]  += p1[3] * v;
      s[8]  += p2[0] * v; s[9]  += p2[1] * v; s[10] += p2[2] * v; s[11] += p2[3] * v;
      s[12] += p3[0] * v; s[13] += p3[1] * v; s[14] += p3[2] * v; s[15] += p3[3] * v;
    }
  }
  __syncthreads();

  // phase 3a: M = V^T V via MFMA; wave strip = M rows [16wv,16wv+16)
  {
    unsigned short* Wk = Wf + (size_t)k * 4608;
    const short8 a0 = *(const short8*)&Vb[16 * wv + jj][8 * q];
    const short8 a1 = *(const short8*)&Vb[16 * wv + jj][8 * q + 32];
#pragma unroll
    for (int t4 = 0; t4 < 4; ++t4) {
      const short8 b0 = *(const short8*)&Vb[jj + 16 * t4][8 * q];
      const short8 b1 = *(const short8*)&Vb[jj + 16 * t4][8 * q + 32];
      float4_ f = {0.f, 0.f, 0.f, 0.f};
      f = __builtin_amdgcn_mfma_f32_16x16x32_bf16(a0, b0, f, 0, 0, 0);
      f = __builtin_amdgcn_mfma_f32_16x16x32_bf16(a1, b1, f, 0, 0, 0);
#pragma unroll
      for (int r = 0; r < 4; ++r)
        Wk[(16 * wv + 4 * q + r) * 72 + jj + 16 * t4] = f2bf(-0.5f * f[r]);
    }
  }
  // wave0: y = V*mu (fp32)
  if (wv == 0) {
    float acc = 0.0f;
    for (int j2 = 0; j2 < 64; ++j2) acc += Vt[j2][lane] * mu_s[j2];
    y_s[lane] = acc;
  }
  __syncthreads();

  // tail (wave0): c = V^T y, beta, write into image pad
  if (t < 64) {
    const int i = t;
    float ci = 0.0f;
#pragma unroll
    for (int m4 = 0; m4 < 16; ++m4) {
      const float4_ a4 = *(const float4_*)&Vt[i][4 * m4];
      const float4_ b4 = *(const float4_*)&y_s[4 * m4];
      ci += a4[0] * b4[0] + a4[1] * b4[1] + a4[2] * b4[2] + a4[3] * b4[3];
    }
    char* Wk = (char*)(Wf + (size_t)k * 4608);
    *(float*)(Wk + i * 144 + 128) = ci;
    float rq  = ci * mu_s[i];
    float dgv = dg[i];
    const float wr = weights_raw[i] * 0.125f;
    float mx = wr;
#pragma unroll
    for (int d = 1; d < 64; d <<= 1) mx = fmaxf(mx, __shfl_xor(mx, d, 64));
    float se = __expf(wr - mx);
#pragma unroll
    for (int d = 1; d < 64; d <<= 1) {
      se  += __shfl_xor(se, d, 64);
      rq  += __shfl_xor(rq, d, 64);
      dgv += __shfl_xor(dgv, d, 64);
    }
    if (i == 0) {
      const float wrk  = weights_raw[k] * 0.125f;
      const float logw = wrk - mx - __logf(se);
      *(float*)(Wk + 132) = -0.5f * rq - 32.0f * LOG_2PI - dgv + logw;
    }
  }
}

// ---------------------------------------------------------------------------
// Main: 1024 blocks x 256 threads, 4 blocks/CU (4 waves/SIMD).
// blockIdx: kh = &3 (16 comps), rt = >>2 (128 rows). Wave owns 32 rows.
// W staged via global_load_lds 16B, KG=2 double-buffered (36.9 KB LDS).
// c/beta read from staged image pad (no per-g global loads).
// Emits bf16 per-row partial exp-sums (shift +90), 4 k-slices.
// ---------------------------------------------------------------------------
__global__ __launch_bounds__(256, 4) void gmm_main(
    const float* __restrict__ x, const unsigned short* __restrict__ Wf,
    unsigned short* __restrict__ ph)
{
  __shared__ __align__(16) unsigned short Wlds[2][2][4608];

  const int t = threadIdx.x;
  const int lane = t & 63;
  const int wv = t >> 6;
  const int q = lane >> 4;
  const int lr = lane & 15;
  const int kh = blockIdx.x & 3;
  const int rt = blockIdx.x >> 2;
  const int rowBase = rt * 128 + wv * 32;
  const int kbase = kh * 16;

  // A fragments: A[m=lr][kdim=8q+32ks+j]
  short8 a[2][2];
#pragma unroll
  for (int mt = 0; mt < 2; ++mt)
#pragma unroll
    for (int ks = 0; ks < 2; ++ks) {
      const float4_* xv = (const float4_*)(x + (size_t)(rowBase + mt * 16 + lr) * 64 + ks * 32 + q * 8);
      const float4_ lo = xv[0], hi = xv[1];
      short8 v;
      v[0] = f2bf(lo[0]); v[1] = f2bf(lo[1]); v[2] = f2bf(lo[2]); v[3] = f2bf(lo[3]);
      v[4] = f2bf(hi[0]); v[5] = f2bf(hi[1]); v[6] = f2bf(hi[2]); v[7] = f2bf(hi[3]);
      a[mt][ks] = v;
    }

  // fp32 x in C layout: xc[mt][t4][r] = x[rowBase+mt*16+4q+r][lr+16*t4]
  float xc[2][4][4];
#pragma unroll
  for (int mt = 0; mt < 2; ++mt)
#pragma unroll
    for (int r = 0; r < 4; ++r) {
      const float* xp = x + (size_t)(rowBase + mt * 16 + q * 4 + r) * 64 + lr;
#pragma unroll
      for (int t4 = 0; t4 < 4; ++t4) xc[mt][t4][r] = xp[16 * t4];
    }

  float sacc[2][4] = {{0, 0, 0, 0}, {0, 0, 0, 0}};

#define STAGE(g, slot)                                                          \
  {                                                                             \
    const unsigned short* src = Wf + (size_t)(kbase + 2 * (g)) * 4608 + t * 8;  \
    unsigned short* dst = &Wlds[slot][0][0] + t * 8;                            \
    async16(src,         dst);                                                  \
    async16(src + 2048,  dst + 2048);                                           \
    async16(src + 4096,  dst + 4096);                                           \
    async16(src + 6144,  dst + 6144);                                           \
    if (t < 128) async16(src + 8192, dst + 8192);                               \
  }

  STAGE(0, 0)
  __syncthreads();

  for (int g = 0; g < 8; ++g) {
    const int cur = g & 1;
    if (g < 7) STAGE(g + 1, cur ^ 1)
#pragma unroll
    for (int kk = 0; kk < 2; ++kk) {
      const unsigned short* wb = &Wlds[cur][kk][0];
      // c / beta from the staged image pad
      float cc[4];
#pragma unroll
      for (int t4 = 0; t4 < 4; ++t4)
        cc[t4] = *(const float*)(wb + (lr + 16 * t4) * 72 + 64);
      const float bk = *(const float*)(wb + 66) + 90.0f;

      short8 b[2][4];
#pragma unroll
      for (int t4 = 0; t4 < 4; ++t4)
#pragma unroll
        for (int ks = 0; ks < 2; ++ks)
          b[ks][t4] = *(const short8*)(wb + (lr + 16 * t4) * 72 + 8 * q + 32 * ks);

      float4_ f[2][4];
#pragma unroll
      for (int mt = 0; mt < 2; ++mt)
#pragma unroll
        for (int t4 = 0; t4 < 4; ++t4) {
          const float cv = cc[t4];
          float4_ acc = {cv, cv, cv, cv};
          acc = __builtin_amdgcn_mfma_f32_16x16x32_bf16(a[mt][0], b[0][t4], acc, 0, 0, 0);
          acc = __builtin_amdgcn_mfma_f32_16x16x32_bf16(a[mt][1], b[1][t4], acc, 0, 0, 0);
          f[mt][t4] = acc;
        }

#pragma unroll
      for (int mt = 0; mt < 2; ++mt)
#pragma unroll
        for (int r = 0; r < 4; ++r) {
          float sdot = xc[mt][0][r] * f[mt][0][r] + xc[mt][1][r] * f[mt][1][r]
                     + xc[mt][2][r] * f[mt][2][r] + xc[mt][3][r] * f[mt][3][r];
          sdot = dpp_add<0x121>(sdot);  // row_ror:1
          sdot = dpp_add<0x122>(sdot);  // row_ror:2
          sdot = dpp_add<0x124>(sdot);  // row_ror:4
          sdot = dpp_add<0x128>(sdot);  // row_ror:8
          sacc[mt][r] += __expf(sdot + bk);
        }
    }
    __syncthreads();
  }
#undef STAGE

  if (lr == 0) {
#pragma unroll
    for (int mt = 0; mt < 2; ++mt)
#pragma unroll
      for (int r = 0; r < 4; ++r)
        ph[(size_t)kh * 32768 + rowBase + mt * 16 + q * 4 + r] = f2bf(sacc[mt][r]);
  }
}

// ---------------------------------------------------------------------------
__global__ __launch_bounds__(256) void gmm_final1(const unsigned short* __restrict__ ph,
                                                  float* __restrict__ p1)
{
  const int t = threadIdx.x;
  const int r0 = blockIdx.x * 512 + t;
  float v = 0.0f;
#pragma unroll
  for (int h = 0; h < 2; ++h) {
    const int row = r0 + 256 * h;
    const float s = bf2f(ph[row]) + bf2f(ph[32768 + row])
                  + bf2f(ph[65536 + row]) + bf2f(ph[98304 + row]);
    v += __logf(s) - 90.0f;
  }
#pragma unroll
  for (int d = 1; d < 64; d <<= 1) v += __shfl_xor(v, d, 64);
  __shared__ float s4[4];
  if ((t & 63) == 0) s4[t >> 6] = v;
  __syncthreads();
  if (t == 0) p1[blockIdx.x] = s4[0] + s4[1] + s4[2] + s4[3];
}

__global__ __launch_bounds__(64) void gmm_final2(const float* __restrict__ p1,
                                                 float* __restrict__ out)
{
  float v = p1[threadIdx.x];
#pragma unroll
  for (int d = 1; d < 64; d <<= 1) v += __shfl_xor(v, d, 64);
  if (threadIdx.x == 0) out[0] = -v * (1.0f / 32768.0f);
}

extern "C" void kernel_launch(void* const* d_in, const int* in_sizes, int n_in,
                              void* d_out, int out_size, void* d_ws, size_t ws_size,
                              hipStream_t stream)
{
  const float* x           = (const float*)d_in[0];  // [32768,64]
  const float* means_raw   = (const float*)d_in[1];  // [64,64]
  const float* scale_raw   = (const float*)d_in[2];  // [64,64,64]
  const float* weights_raw = (const float*)d_in[3];  // [64]
  float* out = (float*)d_out;

  // workspace layout (~852 KB)
  char* ws = (char*)d_ws;
  unsigned short* Wf = (unsigned short*)ws;           // 64*4608*2 = 589824 B
  unsigned short* ph = (unsigned short*)(ws + 589824);// 4*32768*2 = 262144 B
  float* p1          = (float*)(ws + 851968);         // 256 B

  gmm_setup<<<64, 256, 0, stream>>>(means_raw, scale_raw, weights_raw, Wf);
  gmm_main<<<1024, 256, 0, stream>>>(x, Wf, ph);
  gmm_final1<<<64, 256, 0, stream>>>(ph, p1);
  gmm_final2<<<1, 64, 0, stream>>>(p1, out);
}